// Round 1
// baseline (365.789 us; speedup 1.0000x reference)
//
#include <hip/hip_runtime.h>

// ---------------------------------------------------------------------------
// MultiheadAttention (B=4,S=T=2048,QKV=1024,H=8,E=128), weights = 1+tanh
// Pipeline:
//   0) convert q,k,v,Wo fp32->bf16; transpose-convert Wq/Wk/Wv -> [h][e][k]
//   1) k_gemm<0>: qh/kh = x @ W^T + b            ([bh][s][e] bf16)
//      k_gemm<1>: vhT   = (v @ W^T + b)^T        ([bh][e][t] bf16)
//   2) k_attn: per (bh, 128-row s-tile): loop 64-wide t-tiles:
//        S = qh·kh^T ; w = 2/(1+exp2(K*S)) ; acc += w·vh   -> merged bf16
//   3) k_gemm<2>: out = merged @ Wo^T            (fp32)
// All MFMA = v_mfma_f32_16x16x32_bf16 (A row=l&15,k=(l>>4)*8+j; C col=l&15,
// row=(l>>4)*4+i — m89-verified). Attention LDS tiles XOR-swizzled
// (byte ^= (row&7)<<4) with pre-swizzled global_load_lds sources (rule #21).
// ---------------------------------------------------------------------------

using short8 = __attribute__((ext_vector_type(8))) short;
using f32x4  = __attribute__((ext_vector_type(4))) float;
typedef unsigned short u16;

struct alignas(8) us4 { u16 x, y, z, w; };

__device__ __forceinline__ u16 f2bf(float f) {
  union { float f; unsigned u; } v; v.f = f;
  return (u16)((v.u + 0x7FFFu + ((v.u >> 16) & 1u)) >> 16);  // RNE
}

__device__ __forceinline__ void async16(const void* g, void* lds) {
  __builtin_amdgcn_global_load_lds(
      (const __attribute__((address_space(1))) void*)g,
      (__attribute__((address_space(3))) void*)lds, 16, 0, 0);
}

__device__ __forceinline__ f32x4 mfma16(short8 a, short8 b, f32x4 c) {
  return __builtin_amdgcn_mfma_f32_16x16x32_bf16(a, b, c, 0, 0, 0);
}

// ---- fp32 -> bf16 vectorized convert -------------------------------------
__global__ void k_cvt(const float* __restrict__ in, u16* __restrict__ out, int n4) {
  int i = blockIdx.x * blockDim.x + threadIdx.x;
  const int st = gridDim.x * blockDim.x;
  for (; i < n4; i += st) {
    float4 v = reinterpret_cast<const float4*>(in)[i];
    us4 o{f2bf(v.x), f2bf(v.y), f2bf(v.z), f2bf(v.w)};
    reinterpret_cast<us4*>(out)[i] = o;
  }
}

// ---- W[h][k=1024][e=128] -> Wt[h][e=128][k=1024] bf16 --------------------
__global__ void k_wt(const float* __restrict__ W, u16* __restrict__ Wt) {
  __shared__ float t[32][33];
  const int k0 = blockIdx.x * 32, e0 = blockIdx.y * 32, h = blockIdx.z;
  const float* Wh = W + (size_t)h * (1024u * 128u);
  u16* Wth = Wt + (size_t)h * (128u * 1024u);
  const int c = threadIdx.x & 31, r0 = threadIdx.x >> 5;  // 256 thr
  #pragma unroll
  for (int r = r0; r < 32; r += 8) t[r][c] = Wh[(size_t)(k0 + r) * 128 + e0 + c];
  __syncthreads();
  #pragma unroll
  for (int r = r0; r < 32; r += 8)
    Wth[(size_t)(e0 + r) * 1024 + k0 + c] = f2bf(t[c][r]);
}

// ---- generic 128x128-tile GEMM-BT, K=1024, BK=32 (m97 structure) ---------
// MODE 0: bf16 out [bh][2048][128], +bias    (qh / kh)
// MODE 1: bf16 out transposed [bh][128][2048], +bias  (vhT)
// MODE 2: fp32 out [8192][1024], no bias     (out-proj)
template <int MODE>
__global__ __launch_bounds__(256, 3)
void k_gemm(const u16* __restrict__ A, const u16* __restrict__ W,
            const float* __restrict__ bias, void* __restrict__ outp) {
  __shared__ alignas(16) u16 As[128 * 32];
  __shared__ alignas(16) u16 Bs[128 * 32];
  const int tid = threadIdx.x;
  const int lane = tid & 63, wid = tid >> 6;
  const int wr = wid >> 1, wc = wid & 1;
  const int lr = lane & 15, lg = lane >> 4;

  const u16* Ab;
  const u16* Bb;
  const float* bp = nullptr;
  if (MODE <= 1) {
    const int bh = blockIdx.y;
    Ab = A + (size_t)(bh >> 3) * (2048u * 1024u) + (size_t)blockIdx.x * (128u * 1024u);
    Bb = W + (size_t)(bh & 7) * (128u * 1024u);
    bp = bias + (bh & 7) * 128;
  } else {
    Ab = A + (size_t)blockIdx.x * (128u * 1024u);
    Bb = W + (size_t)blockIdx.y * (128u * 1024u);
  }

  f32x4 acc[4][4] = {};

  for (int k0 = 0; k0 < 1024; k0 += 32) {
    #pragma unroll
    for (int p = 0; p < 2; ++p) {
      const int ch = p * 256 + tid;  // 512 chunks x 16B per tile
      const int row = ch >> 2, cc = ch & 3;
      async16(Ab + (size_t)row * 1024 + k0 + cc * 8, &As[ch * 8]);
      async16(Bb + (size_t)row * 1024 + k0 + cc * 8, &Bs[ch * 8]);
    }
    __syncthreads();
    short8 a[4], b[4];
    #pragma unroll
    for (int m = 0; m < 4; ++m)
      a[m] = *(const short8*)&As[(wr * 64 + m * 16 + lr) * 32 + lg * 8];
    #pragma unroll
    for (int n = 0; n < 4; ++n)
      b[n] = *(const short8*)&Bs[(wc * 64 + n * 16 + lr) * 32 + lg * 8];
    #pragma unroll
    for (int m = 0; m < 4; ++m)
      #pragma unroll
      for (int n = 0; n < 4; ++n)
        acc[m][n] = mfma16(a[m], b[n], acc[m][n]);
    __syncthreads();
  }

  if (MODE == 0) {
    u16* O = (u16*)outp + (size_t)blockIdx.y * (2048u * 128u) + (size_t)blockIdx.x * (128u * 128u);
    #pragma unroll
    for (int n = 0; n < 4; ++n) {
      const int e = wc * 64 + n * 16 + lr;
      const float bv = bp[e];
      #pragma unroll
      for (int m = 0; m < 4; ++m) {
        const int r0 = wr * 64 + m * 16 + lg * 4;
        #pragma unroll
        for (int i = 0; i < 4; ++i)
          O[(size_t)(r0 + i) * 128 + e] = f2bf(acc[m][n][i] + bv);
      }
    }
  } else if (MODE == 1) {
    u16* O = (u16*)outp + (size_t)blockIdx.y * (128u * 2048u);
    #pragma unroll
    for (int n = 0; n < 4; ++n) {
      const int e = wc * 64 + n * 16 + lr;
      const float bv = bp[e];
      #pragma unroll
      for (int m = 0; m < 4; ++m) {
        const int t = blockIdx.x * 128 + wr * 64 + m * 16 + lg * 4;
        us4 o{f2bf(acc[m][n][0] + bv), f2bf(acc[m][n][1] + bv),
              f2bf(acc[m][n][2] + bv), f2bf(acc[m][n][3] + bv)};
        *(us4*)&O[(size_t)e * 2048 + t] = o;
      }
    }
  } else {
    float* O = (float*)outp + (size_t)blockIdx.x * (128u * 1024u) + blockIdx.y * 128;
    #pragma unroll
    for (int m = 0; m < 4; ++m)
      #pragma unroll
      for (int n = 0; n < 4; ++n)
        #pragma unroll
        for (int i = 0; i < 4; ++i)
          O[(size_t)(wr * 64 + m * 16 + lg * 4 + i) * 1024 + wc * 64 + n * 16 + lr] =
              acc[m][n][i];
  }
}

// ---- fused attention: S = qh.kh^T; w = 1+tanh(S/sqrt(E)); acc += w.vh ----
__global__ __launch_bounds__(256, 2)
void k_attn(const u16* __restrict__ QH, const u16* __restrict__ KH,
            const u16* __restrict__ VT, u16* __restrict__ MG) {
  __shared__ alignas(16) u16 Ks[64 * 128];   // [t][e], swizzled
  __shared__ alignas(16) u16 Vs[128 * 64];   // [e][t], swizzled
  __shared__ alignas(16) u16 Ws[128 * 64];   // [s][t], swizzled, per-wave rows
  const int tid = threadIdx.x, lane = tid & 63, wid = tid >> 6;
  const int lr = lane & 15, lg = lane >> 4;
  const int bh = blockIdx.y, b = bh >> 3, h = bh & 7;
  const int s0 = blockIdx.x * 128;
  const u16* Qb = QH + (size_t)bh * (2048u * 128u);
  const u16* Kb = KH + (size_t)bh * (2048u * 128u);
  const u16* Vb = VT + (size_t)bh * (128u * 2048u);

  // Q fragments held in registers for the whole block (rows wid*32..+31)
  short8 qa[2][4];
  #pragma unroll
  for (int m = 0; m < 2; ++m)
    #pragma unroll
    for (int ks = 0; ks < 4; ++ks)
      qa[m][ks] = *(const short8*)&Qb[(size_t)(s0 + wid * 32 + m * 16 + lr) * 128 + ks * 32 + lg * 8];

  f32x4 racc[2][8] = {};
  const int kx = (lr & 7) << 4;            // read-side XOR (rows == n*16+lr)
  const float KSC = -0.25503486f;          // -2*log2(e)/sqrt(128)

  for (int tt = 0; tt < 32; ++tt) {
    const int t0 = tt * 64;
    // stage K-tile: 64 rows x 16 chunks, source pre-swizzled (rule #21)
    #pragma unroll
    for (int p = 0; p < 4; ++p) {
      const int ch = p * 256 + tid;
      const int r = ch >> 4, cc = ch & 15;
      async16(Kb + (size_t)(t0 + r) * 128 + ((cc ^ (r & 7)) * 8), &Ks[ch * 8]);
    }
    // stage V-tile: 128 rows x 8 chunks
    #pragma unroll
    for (int p = 0; p < 4; ++p) {
      const int ch = p * 256 + tid;
      const int r = ch >> 3, cc = ch & 7;
      async16(Vb + (size_t)r * 2048 + t0 + ((cc ^ (r & 7)) * 8), &Vs[ch * 8]);
    }
    __syncthreads();

    // scores: [32s x 64t] per wave, K=128
    f32x4 sacc[2][4] = {};
    #pragma unroll
    for (int ks = 0; ks < 4; ++ks)
      #pragma unroll
      for (int n = 0; n < 4; ++n) {
        const int krow = n * 16 + lr;
        const short8 kb =
            *(const short8*)((const char*)Ks + krow * 256 + ((ks * 64 + lg * 16) ^ kx));
        sacc[0][n] = mfma16(qa[0][ks], kb, sacc[0][n]);
        sacc[1][n] = mfma16(qa[1][ks], kb, sacc[1][n]);
      }

    // w = 1 + tanh(s/sqrt(128)) = 2*rcp(1+exp2(KSC*s)); write bf16 -> Ws
    #pragma unroll
    for (int m = 0; m < 2; ++m)
      #pragma unroll
      for (int n = 0; n < 4; ++n)
        #pragma unroll
        for (int i = 0; i < 4; ++i) {
          const float x = sacc[m][n][i];
          const float wv =
              2.f * __builtin_amdgcn_rcpf(1.f + __builtin_amdgcn_exp2f(x * KSC));
          const int srow = wid * 32 + m * 16 + lg * 4 + i;
          const int tcol = n * 16 + lr;
          *(u16*)((char*)Ws + srow * 128 + ((tcol * 2) ^ ((srow & 7) << 4))) = f2bf(wv);
        }

    // PV: racc += W[32s x 64t] . vh[64t x 128e]   (same-wave LDS, no barrier)
    short8 pa[2][2];
    #pragma unroll
    for (int m = 0; m < 2; ++m)
      #pragma unroll
      for (int ks = 0; ks < 2; ++ks) {
        const int prow = wid * 32 + m * 16 + lr;
        pa[m][ks] =
            *(const short8*)((const char*)Ws + prow * 128 + ((ks * 64 + lg * 16) ^ kx));
      }
    #pragma unroll
    for (int ks = 0; ks < 2; ++ks)
      #pragma unroll
      for (int n = 0; n < 8; ++n) {
        const int vrow = n * 16 + lr;
        const short8 vb =
            *(const short8*)((const char*)Vs + vrow * 128 + ((ks * 64 + lg * 16) ^ kx));
        racc[0][n] = mfma16(pa[0][ks], vb, racc[0][n]);
        racc[1][n] = mfma16(pa[1][ks], vb, racc[1][n]);
      }
    __syncthreads();
  }

  // merged[b][s][h*128+e] bf16
  u16* Mb = MG + ((size_t)(b * 2048 + s0)) * 1024 + h * 128;
  #pragma unroll
  for (int m = 0; m < 2; ++m)
    #pragma unroll
    for (int n = 0; n < 8; ++n) {
      const int e = n * 16 + lr;
      #pragma unroll
      for (int i = 0; i < 4; ++i) {
        const int srow = wid * 32 + m * 16 + lg * 4 + i;
        Mb[(size_t)srow * 1024 + e] = f2bf(racc[m][n][i]);
      }
    }
}

// ---------------------------------------------------------------------------
extern "C" void kernel_launch(void* const* d_in, const int* in_sizes, int n_in,
                              void* d_out, int out_size, void* d_ws, size_t ws_size,
                              hipStream_t stream) {
  (void)in_sizes; (void)n_in; (void)out_size; (void)ws_size;
  const float* q  = (const float*)d_in[0];
  const float* k  = (const float*)d_in[1];
  const float* v  = (const float*)d_in[2];
  const float* Wq = (const float*)d_in[3];
  const float* bq = (const float*)d_in[4];
  const float* Wk = (const float*)d_in[5];
  const float* bk = (const float*)d_in[6];
  const float* Wv = (const float*)d_in[7];
  const float* bv = (const float*)d_in[8];
  const float* Wo = (const float*)d_in[9];

  char* ws = (char*)d_ws;
  const size_t MB16 = 16777216;  // 16 MiB regions (B*S*1024 bf16)
  u16* qb  = (u16*)(ws + 0 * MB16);
  u16* kb  = (u16*)(ws + 1 * MB16);
  u16* vb  = (u16*)(ws + 2 * MB16);
  u16* qh  = (u16*)(ws + 3 * MB16);
  u16* kh  = (u16*)(ws + 4 * MB16);
  u16* vT  = (u16*)(ws + 5 * MB16);
  u16* wqt = (u16*)(ws + 6 * MB16);
  u16* wkt = (u16*)(ws + 6 * MB16 + 1 * 2097152);
  u16* wvt = (u16*)(ws + 6 * MB16 + 2 * 2097152);
  u16* wob = (u16*)(ws + 6 * MB16 + 3 * 2097152);
  u16* mg  = qb;  // alias: qb is dead once the q-projection has run

  // 0) dtype conversions / weight transposes
  k_cvt<<<2048, 256, 0, stream>>>(q, qb, 2097152);
  k_cvt<<<2048, 256, 0, stream>>>(k, kb, 2097152);
  k_cvt<<<2048, 256, 0, stream>>>(v, vb, 2097152);
  k_cvt<<<1024, 256, 0, stream>>>(Wo, wob, 262144);
  k_wt<<<dim3(32, 4, 8), 256, 0, stream>>>(Wq, wqt);
  k_wt<<<dim3(32, 4, 8), 256, 0, stream>>>(Wk, wkt);
  k_wt<<<dim3(32, 4, 8), 256, 0, stream>>>(Wv, wvt);

  // 1) per-head projections
  k_gemm<0><<<dim3(16, 32), 256, 0, stream>>>(qb, wqt, bq, qh);
  k_gemm<0><<<dim3(16, 32), 256, 0, stream>>>(kb, wkt, bk, kh);
  k_gemm<1><<<dim3(16, 32), 256, 0, stream>>>(vb, wvt, bv, vT);

  // 2) fused attention -> merged
  k_attn<<<dim3(16, 32), 256, 0, stream>>>(qh, kh, vT, mg);

  // 3) output projection (fp32 out)
  k_gemm<2><<<dim3(64, 8), 256, 0, stream>>>(mg, wob, nullptr, d_out);
}

// Round 6
// 326.244 us; speedup vs baseline: 1.1212x; 1.1212x over previous
//
#include <hip/hip_runtime.h>

// ---------------------------------------------------------------------------
// MultiheadAttention (B=4,S=T=2048,QKV=1024,H=8,E=128), weights = 1+tanh
//   0) k_cvt3: q,k,v fp32->bf16 ; k_cvt: Wo fp32->bf16 SCALED BY 2
//      k_wt3: Wq/Wk/Wv -> [h][e][k] bf16
//   1) k_proj (merged q,k,v): qh/kh = x @ W^T + b ([bh][s][e] bf16),
//      vhT = (v @ W^T + b)^T ([bh][e][t] bf16). BK=64, XOR-swizzled LDS.
//   2) k_attn: 32x32 MFMA swapped QK^T -> S^T in regs; w'=sigma(2*s/sqrt128)
//      in regs (x2 folded into Wo); repack to PV A-frags via manual bf16 pack
//      + __shfl_xor(32) + selects (verified primitives only); PV mfma32.
//      K/V double-buffered, XOR-swizzled, global_load_lds w/ pre-swizzled src.
//   3) k_gemmO: out = merged @ (2*Wo)^T (fp32), BK=64.
// ---------------------------------------------------------------------------

using short8 = __attribute__((ext_vector_type(8))) short;
using f32x4  = __attribute__((ext_vector_type(4))) float;
using f32x16 = __attribute__((ext_vector_type(16))) float;
using v4i    = __attribute__((ext_vector_type(4))) int;
typedef unsigned short u16;

struct alignas(8) us4 { u16 x, y, z, w; };

__device__ __forceinline__ u16 f2bf(float f) {
  union { float f; unsigned u; } v; v.f = f;
  return (u16)((v.u + 0x7FFFu + ((v.u >> 16) & 1u)) >> 16);  // RNE
}
__device__ __forceinline__ unsigned packbf(float lo, float hi) {
  return (unsigned)f2bf(lo) | ((unsigned)f2bf(hi) << 16);
}

__device__ __forceinline__ void async16(const void* g, void* lds) {
  __builtin_amdgcn_global_load_lds(
      (const __attribute__((address_space(1))) void*)g,
      (__attribute__((address_space(3))) void*)lds, 16, 0, 0);
}

__device__ __forceinline__ f32x4 mfma16(short8 a, short8 b, f32x4 c) {
  return __builtin_amdgcn_mfma_f32_16x16x32_bf16(a, b, c, 0, 0, 0);
}
__device__ __forceinline__ f32x16 mfma32(short8 a, short8 b, f32x16 c) {
  return __builtin_amdgcn_mfma_f32_32x32x16_bf16(a, b, c, 0, 0, 0);
}

// ---- fp32 -> bf16 convert (optionally scaled) ----------------------------
__global__ void k_cvt(const float* __restrict__ in, u16* __restrict__ out,
                      int n4, float scale) {
  int i = blockIdx.x * blockDim.x + threadIdx.x;
  const int st = gridDim.x * blockDim.x;
  for (; i < n4; i += st) {
    float4 v = reinterpret_cast<const float4*>(in)[i];
    us4 o{f2bf(v.x * scale), f2bf(v.y * scale), f2bf(v.z * scale), f2bf(v.w * scale)};
    reinterpret_cast<us4*>(out)[i] = o;
  }
}

// ---- q,k,v fp32 -> bf16 in one launch ------------------------------------
__global__ void k_cvt3(const float* __restrict__ a, const float* __restrict__ b,
                       const float* __restrict__ c, u16* __restrict__ oa,
                       u16* __restrict__ ob, u16* __restrict__ oc) {
  const float* in = (blockIdx.y == 0) ? a : (blockIdx.y == 1) ? b : c;
  u16* out = (blockIdx.y == 0) ? oa : (blockIdx.y == 1) ? ob : oc;
  int i = blockIdx.x * blockDim.x + threadIdx.x;
  const int st = gridDim.x * blockDim.x;
  for (; i < 2097152; i += st) {
    float4 v = reinterpret_cast<const float4*>(in)[i];
    us4 o{f2bf(v.x), f2bf(v.y), f2bf(v.z), f2bf(v.w)};
    reinterpret_cast<us4*>(out)[i] = o;
  }
}

// ---- W[h][k=1024][e=128] -> Wt[h][e=128][k=1024] bf16, all 3 weights -----
__global__ void k_wt3(const float* __restrict__ Wa, const float* __restrict__ Wb,
                      const float* __restrict__ Wc, u16* __restrict__ Ta,
                      u16* __restrict__ Tb, u16* __restrict__ Tc) {
  __shared__ float t[32][33];
  const int z = blockIdx.z, h = z & 7, which = z >> 3;
  const float* W = (which == 0) ? Wa : (which == 1) ? Wb : Wc;
  u16* Wt = (which == 0) ? Ta : (which == 1) ? Tb : Tc;
  const int k0 = blockIdx.x * 32, e0 = blockIdx.y * 32;
  const float* Wh = W + (size_t)h * (1024u * 128u);
  u16* Wth = Wt + (size_t)h * (128u * 1024u);
  const int c = threadIdx.x & 31, r0 = threadIdx.x >> 5;  // 256 thr
  #pragma unroll
  for (int r = r0; r < 32; r += 8) t[r][c] = Wh[(size_t)(k0 + r) * 128 + e0 + c];
  __syncthreads();
  #pragma unroll
  for (int r = r0; r < 32; r += 8)
    Wth[(size_t)(e0 + r) * 1024 + k0 + c] = f2bf(t[c][r]);
}

// ---- merged q/k/v projection GEMM: 128x128 tile, BK=64, swizzled LDS -----
// grid (16, 96): y = which*32 + bh. which 0/1 -> normal store (qh/kh);
// which 2 -> transposed store (vT).
__global__ __launch_bounds__(256, 3)
void k_proj(const u16* __restrict__ qb, const u16* __restrict__ kb,
            const u16* __restrict__ vb, const u16* __restrict__ wq,
            const u16* __restrict__ wk, const u16* __restrict__ wv,
            const float* __restrict__ bq, const float* __restrict__ bk,
            const float* __restrict__ bv, u16* __restrict__ qh,
            u16* __restrict__ kh, u16* __restrict__ vT) {
  __shared__ alignas(16) u16 As[128 * 64];
  __shared__ alignas(16) u16 Bs[128 * 64];
  const int tid = threadIdx.x;
  const int lane = tid & 63, wid = tid >> 6;
  const int wr = wid >> 1, wc = wid & 1;
  const int lr = lane & 15, lg = lane >> 4;
  const int y = blockIdx.y, which = y >> 5, bh = y & 31;

  const u16* A = (which == 0) ? qb : (which == 1) ? kb : vb;
  const u16* W = (which == 0) ? wq : (which == 1) ? wk : wv;
  const float* bias = (which == 0) ? bq : (which == 1) ? bk : bv;
  const u16* Ab = A + (size_t)(bh >> 3) * (2048u * 1024u) + (size_t)blockIdx.x * (128u * 1024u);
  const u16* Bb = W + (size_t)(bh & 7) * (128u * 1024u);
  const float* bp = bias + (bh & 7) * 128;

  f32x4 acc[4][4] = {};
  const int rx = (lr & 7) << 4;  // read-side XOR for fragment rows

  for (int k0 = 0; k0 < 1024; k0 += 64) {
    #pragma unroll
    for (int p = 0; p < 4; ++p) {
      const int ch = p * 256 + tid;  // 1024 chunks of 16B per tile
      const int r = ch >> 3, cc = ch & 7;
      const size_t goff = (size_t)r * 1024 + k0 + ((cc ^ (r & 7)) * 8);
      async16(Ab + goff, (char*)As + ch * 16);
      async16(Bb + goff, (char*)Bs + ch * 16);
    }
    __syncthreads();
    #pragma unroll
    for (int kk = 0; kk < 2; ++kk) {
      short8 a[4], b[4];
      #pragma unroll
      for (int m = 0; m < 4; ++m)
        a[m] = *(const short8*)((const char*)As + (wr * 64 + m * 16 + lr) * 128 +
                                ((kk * 64 + lg * 16) ^ rx));
      #pragma unroll
      for (int n = 0; n < 4; ++n)
        b[n] = *(const short8*)((const char*)Bs + (wc * 64 + n * 16 + lr) * 128 +
                                ((kk * 64 + lg * 16) ^ rx));
      #pragma unroll
      for (int m = 0; m < 4; ++m)
        #pragma unroll
        for (int n = 0; n < 4; ++n)
          acc[m][n] = mfma16(a[m], b[n], acc[m][n]);
    }
    __syncthreads();
  }

  if (which < 2) {
    u16* O = ((which == 0) ? qh : kh) + (size_t)bh * (2048u * 128u) +
             (size_t)blockIdx.x * (128u * 128u);
    #pragma unroll
    for (int n = 0; n < 4; ++n) {
      const int e = wc * 64 + n * 16 + lr;
      const float bvv = bp[e];
      #pragma unroll
      for (int m = 0; m < 4; ++m) {
        const int r0 = wr * 64 + m * 16 + lg * 4;
        #pragma unroll
        for (int i = 0; i < 4; ++i)
          O[(size_t)(r0 + i) * 128 + e] = f2bf(acc[m][n][i] + bvv);
      }
    }
  } else {
    u16* O = vT + (size_t)bh * (128u * 2048u);
    #pragma unroll
    for (int n = 0; n < 4; ++n) {
      const int e = wc * 64 + n * 16 + lr;
      const float bvv = bp[e];
      #pragma unroll
      for (int m = 0; m < 4; ++m) {
        const int t = blockIdx.x * 128 + wr * 64 + m * 16 + lg * 4;
        us4 o{f2bf(acc[m][n][0] + bvv), f2bf(acc[m][n][1] + bvv),
              f2bf(acc[m][n][2] + bvv), f2bf(acc[m][n][3] + bvv)};
        *(us4*)&O[(size_t)e * 2048 + t] = o;
      }
    }
  }
}

// ---- out-proj GEMM: out[8192][1024] = mg @ Wo2^T, BK=64, fp32 out --------
__global__ __launch_bounds__(256, 3)
void k_gemmO(const u16* __restrict__ A, const u16* __restrict__ W,
             float* __restrict__ O) {
  __shared__ alignas(16) u16 As[128 * 64];
  __shared__ alignas(16) u16 Bs[128 * 64];
  const int tid = threadIdx.x;
  const int lane = tid & 63, wid = tid >> 6;
  const int wr = wid >> 1, wc = wid & 1;
  const int lr = lane & 15, lg = lane >> 4;
  const u16* Ab = A + (size_t)blockIdx.x * (128u * 1024u);
  const u16* Bb = W + (size_t)blockIdx.y * (128u * 1024u);

  f32x4 acc[4][4] = {};
  const int rx = (lr & 7) << 4;

  for (int k0 = 0; k0 < 1024; k0 += 64) {
    #pragma unroll
    for (int p = 0; p < 4; ++p) {
      const int ch = p * 256 + tid;
      const int r = ch >> 3, cc = ch & 7;
      const size_t goff = (size_t)r * 1024 + k0 + ((cc ^ (r & 7)) * 8);
      async16(Ab + goff, (char*)As + ch * 16);
      async16(Bb + goff, (char*)Bs + ch * 16);
    }
    __syncthreads();
    #pragma unroll
    for (int kk = 0; kk < 2; ++kk) {
      short8 a[4], b[4];
      #pragma unroll
      for (int m = 0; m < 4; ++m)
        a[m] = *(const short8*)((const char*)As + (wr * 64 + m * 16 + lr) * 128 +
                                ((kk * 64 + lg * 16) ^ rx));
      #pragma unroll
      for (int n = 0; n < 4; ++n)
        b[n] = *(const short8*)((const char*)Bs + (wc * 64 + n * 16 + lr) * 128 +
                                ((kk * 64 + lg * 16) ^ rx));
      #pragma unroll
      for (int m = 0; m < 4; ++m)
        #pragma unroll
        for (int n = 0; n < 4; ++n)
          acc[m][n] = mfma16(a[m], b[n], acc[m][n]);
    }
    __syncthreads();
  }

  float* Ob = O + (size_t)blockIdx.x * (128u * 1024u) + blockIdx.y * 128;
  #pragma unroll
  for (int m = 0; m < 4; ++m)
    #pragma unroll
    for (int n = 0; n < 4; ++n)
      #pragma unroll
      for (int i = 0; i < 4; ++i)
        Ob[(size_t)(wr * 64 + m * 16 + lg * 4 + i) * 1024 + wc * 64 + n * 16 + lr] =
            acc[m][n][i];
}

// ---- fused attention: 32x32 swapped QK^T, in-reg sigma, shfl repack ------
// Wave w owns s-rows [s0+32w,+32). Per 64-t tile: 2 t-blocks of 32.
// p[r] = S^T[t=(r&3)+8*(r>>2)+4*hi][s=sl] (m74/m101 C/D layout).
// PV A-frag ks needs P[s=sl][t=tb*32+ks*16+hi*8+j] -> build via manual pack
// (lo = even t) + __shfl_xor(32) partner fetch + hi-selects.
__global__ __launch_bounds__(256, 2)
void k_attn(const u16* __restrict__ QH, const u16* __restrict__ KH,
            const u16* __restrict__ VT, u16* __restrict__ MG) {
  __shared__ alignas(16) u16 Ks[2][64 * 128];   // [t][e], swizzled
  __shared__ alignas(16) u16 Vs[2][128 * 64];   // [e][t], swizzled
  const int tid = threadIdx.x, lane = tid & 63, wid = tid >> 6;
  const int sl = lane & 31, hi = lane >> 5;
  const int bh = blockIdx.y, b = bh >> 3, h = bh & 7;
  const int s0 = blockIdx.x * 128;
  const u16* Qb = QH + (size_t)bh * (2048u * 128u);
  const u16* Kb = KH + (size_t)bh * (2048u * 128u);
  const u16* Vb = VT + (size_t)bh * (128u * 2048u);
  const float KSC = -0.25503473f;  // -2*log2(e)/sqrt(128)

  // Q b-fragments: qf[ke][j] = Q[s0+32w+sl][16ke+8hi+j]
  short8 qf[8];
  {
    const u16* Qp = Qb + (size_t)(s0 + 32 * wid + sl) * 128 + hi * 8;
    #pragma unroll
    for (int ke = 0; ke < 8; ++ke) qf[ke] = *(const short8*)(Qp + ke * 16);
  }

  f32x16 racc[4] = {};
  const int swr = (sl & 7) << 4;  // read-side XOR (rows indexed by sl)

  auto STAGE = [&](int buf, int t0) {
    #pragma unroll
    for (int p = 0; p < 4; ++p) {
      const int ch = p * 256 + tid;        // K: 64 rows x 16 chunks
      const int r = ch >> 4, cc = ch & 15;
      async16(Kb + (size_t)(t0 + r) * 128 + ((cc ^ (r & 7)) * 8), &Ks[buf][ch * 8]);
    }
    #pragma unroll
    for (int p = 0; p < 4; ++p) {
      const int ch = p * 256 + tid;        // V: 128 rows x 8 chunks
      const int r = ch >> 3, cc = ch & 7;
      async16(Vb + (size_t)r * 2048 + t0 + ((cc ^ (r & 7)) * 8), &Vs[buf][ch * 8]);
    }
  };

  STAGE(0, 0);
  __syncthreads();

  for (int tt = 0; tt < 32; ++tt) {
    const int cur = tt & 1;
    if (tt < 31) STAGE(cur ^ 1, (tt + 1) * 64);

    const char* KsB = (const char*)Ks[cur];
    const char* VsB = (const char*)Vs[cur];
    #pragma unroll
    for (int tb = 0; tb < 2; ++tb) {
      // --- swapped QK^T ---------------------------------------------------
      f32x16 p = {};
      const int krow = tb * 32 + sl;
      __builtin_amdgcn_s_setprio(1);
      #pragma unroll
      for (int ke = 0; ke < 8; ++ke) {
        const short8 kf = *(const short8*)(KsB + krow * 256 + ((ke * 32 + hi * 16) ^ swr));
        p = mfma32(kf, qf[ke], p);
      }
      __builtin_amdgcn_s_setprio(0);

      // --- sigma + pack pairs (lo = even/smaller t) -----------------------
      unsigned qpk[8];
      #pragma unroll
      for (int i = 0; i < 8; ++i) {
        const float w0 = __builtin_amdgcn_rcpf(1.f + __builtin_amdgcn_exp2f(p[2 * i] * KSC));
        const float w1 = __builtin_amdgcn_rcpf(1.f + __builtin_amdgcn_exp2f(p[2 * i + 1] * KSC));
        qpk[i] = packbf(w0, w1);
      }
      // --- cross-half exchange via verified shfl_xor(32) ------------------
      unsigned o0 = __shfl_xor(qpk[0], 32), o1 = __shfl_xor(qpk[1], 32);
      unsigned o2 = __shfl_xor(qpk[2], 32), o3 = __shfl_xor(qpk[3], 32);
      unsigned o4 = __shfl_xor(qpk[4], 32), o5 = __shfl_xor(qpk[5], 32);
      unsigned o6 = __shfl_xor(qpk[6], 32), o7 = __shfl_xor(qpk[7], 32);
      union PK { v4i i; short8 s; } pk0, pk1;
      // frag ks=0: t = tb*32 + hi*8 + {0..7} as dwords (t even, t odd)
      pk0.i = (v4i){(int)(hi ? o2 : qpk[0]), (int)(hi ? o3 : qpk[1]),
                    (int)(hi ? qpk[2] : o0), (int)(hi ? qpk[3] : o1)};
      // frag ks=1: t = tb*32 + 16 + hi*8 + {0..7}
      pk1.i = (v4i){(int)(hi ? o6 : qpk[4]), (int)(hi ? o7 : qpk[5]),
                    (int)(hi ? qpk[6] : o4), (int)(hi ? qpk[7] : o5)};

      // --- PV -------------------------------------------------------------
      __builtin_amdgcn_s_setprio(1);
      #pragma unroll
      for (int ks = 0; ks < 2; ++ks) {
        const short8 pf = ks ? pk1.s : pk0.s;
        #pragma unroll
        for (int eb = 0; eb < 4; ++eb) {
          const int vrow = eb * 32 + sl;
          const short8 vf = *(const short8*)(
              VsB + vrow * 128 + ((tb * 64 + ks * 32 + hi * 16) ^ swr));
          racc[eb] = mfma32(pf, vf, racc[eb]);
        }
      }
      __builtin_amdgcn_s_setprio(0);
    }
    __syncthreads();
  }

  // merged[b][s][h*128+e]; s = s0+32w+(r&3)+8*(r>>2)+4hi, e = 32eb+sl
  u16* Mb = MG + ((size_t)(b * 2048 + s0 + 32 * wid)) * 1024 + h * 128;
  #pragma unroll
  for (int eb = 0; eb < 4; ++eb)
    #pragma unroll
    for (int r = 0; r < 16; ++r) {
      const int srow = (r & 3) + 8 * (r >> 2) + 4 * hi;
      Mb[(size_t)srow * 1024 + eb * 32 + sl] = f2bf(racc[eb][r]);
    }
}

// ---------------------------------------------------------------------------
extern "C" void kernel_launch(void* const* d_in, const int* in_sizes, int n_in,
                              void* d_out, int out_size, void* d_ws, size_t ws_size,
                              hipStream_t stream) {
  (void)in_sizes; (void)n_in; (void)out_size; (void)ws_size;
  const float* q  = (const float*)d_in[0];
  const float* k  = (const float*)d_in[1];
  const float* v  = (const float*)d_in[2];
  const float* Wq = (const float*)d_in[3];
  const float* bq = (const float*)d_in[4];
  const float* Wk = (const float*)d_in[5];
  const float* bk = (const float*)d_in[6];
  const float* Wv = (const float*)d_in[7];
  const float* bv = (const float*)d_in[8];
  const float* Wo = (const float*)d_in[9];

  char* ws = (char*)d_ws;
  const size_t MB16 = 16777216;  // 16 MiB regions (B*S*1024 bf16)
  u16* qb  = (u16*)(ws + 0 * MB16);
  u16* kb  = (u16*)(ws + 1 * MB16);
  u16* vb  = (u16*)(ws + 2 * MB16);
  u16* qh  = (u16*)(ws + 3 * MB16);
  u16* kh  = (u16*)(ws + 4 * MB16);
  u16* vT  = (u16*)(ws + 5 * MB16);
  u16* wqt = (u16*)(ws + 6 * MB16);
  u16* wkt = (u16*)(ws + 6 * MB16 + 1 * 2097152);
  u16* wvt = (u16*)(ws + 6 * MB16 + 2 * 2097152);
  u16* wob = (u16*)(ws + 6 * MB16 + 3 * 2097152);
  u16* mg  = qb;  // alias: qb is dead once the q-projection has run

  // 0) dtype conversions / weight transposes (2x folded into Wo)
  k_cvt3<<<dim3(2048, 3), 256, 0, stream>>>(q, k, v, qb, kb, vb);
  k_cvt<<<1024, 256, 0, stream>>>(Wo, wob, 262144, 2.0f);
  k_wt3<<<dim3(32, 4, 24), 256, 0, stream>>>(Wq, Wk, Wv, wqt, wkt, wvt);

  // 1) merged per-head projections (q,k normal; v transposed)
  k_proj<<<dim3(16, 96), 256, 0, stream>>>(qb, kb, vb, wqt, wkt, wvt,
                                           bq, bk, bv, qh, kh, vT);

  // 2) fused attention -> merged (sigma-weighted; 2x lives in Wo)
  k_attn<<<dim3(16, 32), 256, 0, stream>>>(qh, kh, vT, mg);

  // 3) output projection (fp32 out)
  k_gemmO<<<dim3(64, 8), 256, 0, stream>>>(mg, wob, (float*)d_out);
}